// Round 1
// baseline (61.987 us; speedup 1.0000x reference)
//
#include <hip/hip_runtime.h>
#include <math.h>

// YOLOv1 decode + greedy NMS, S=7 grid, 2 boxes, 20 classes.
// Tiny problem (1470 floats in, 343 out): single block, single wave of 64
// lanes does decode (lanes 0..48 = cells), rank-based stable sort, and the
// sequential NMS loop via __shfl broadcasts.

#define NUM_CLASSES 20
#define S 7
#define NCELL 49            // S*S boxes
#define CONF_THR 0.25f
#define IOU_THR 0.45f
#define EPS_IOU 1e-6f
#define CELL_STRIDE 64.0f   // 448 / 7

__device__ __forceinline__ float sigmoidf(float v) {
    return 1.0f / (1.0f + expf(-v));
}

__global__ __launch_bounds__(64) void yolo_decode_nms(const float* __restrict__ x,
                                                      float* __restrict__ out) {
    const int j = threadIdx.x;  // 0..63, one wave

    __shared__ float s_box[NCELL][6];     // decoded: cls, conf, cx, cy, w, h
    __shared__ float s_sorted[NCELL][6];  // after stable descending sort by conf

    // ---- decode ----
    if (j < NCELL) {
        const float* c = x + j * (NUM_CLASSES + 10);

        // class argmax over raw logits (sigmoid is strictly monotonic;
        // first-index tie-break matches jnp.argmax)
        int ci = 0;
        float cmax = c[0];
        #pragma unroll
        for (int k = 1; k < NUM_CLASSES; ++k) {
            float v = c[k];
            if (v > cmax) { cmax = v; ci = k; }
        }

        // best of 2 boxes by conf logit; tie -> index 0 (matches jnp.argmax)
        float c0 = c[NUM_CLASSES + 0];       // conf logit box 0 (ch 20)
        float c1 = c[NUM_CLASSES + 5];       // conf logit box 1 (ch 25)
        int best = (c1 > c0) ? 1 : 0;
        int boff = NUM_CLASSES + 1 + 5 * best;  // 21 or 26

        float conf = sigmoidf(best ? c1 : c0);
        float bx = sigmoidf(c[boff + 0]);
        float by = sigmoidf(c[boff + 1]);
        float bw = sigmoidf(c[boff + 2]);
        float bh = sigmoidf(c[boff + 3]);

        int row = j / S, col = j % S;   // x index = col (meshgrid 'xy'), y = row

        s_box[j][0] = (float)ci;
        s_box[j][1] = conf;
        s_box[j][2] = (bx + (float)col) * CELL_STRIDE;
        s_box[j][3] = (by + (float)row) * CELL_STRIDE;
        s_box[j][4] = bw * (float)S * CELL_STRIDE;  // bw * W * stride = bw*448
        s_box[j][5] = bh * (float)S * CELL_STRIDE;
    }
    __syncthreads();

    // ---- stable descending sort by conf (rank scatter, matches
    //      jnp.argsort(-conf) stable tie-break by original index) ----
    if (j < NCELL) {
        float myconf = s_box[j][1];
        int rank = 0;
        for (int k = 0; k < NCELL; ++k) {
            float ck = s_box[k][1];
            rank += (ck > myconf) || (ck == myconf && k < j);
        }
        #pragma unroll
        for (int t = 0; t < 6; ++t) s_sorted[rank][t] = s_box[j][t];
    }
    __syncthreads();

    // ---- greedy NMS: lane j owns sorted box j; 49-iter wave loop.
    //      Lane i's keep is only ever modified by iterations < i, so
    //      __shfl(keep, i) at iteration i equals the sequential keep[i]. ----
    float cls = 0.f, conf = 0.f, cx = 0.f, cy = 0.f, w = 0.f, h = 0.f;
    if (j < NCELL) {
        cls  = s_sorted[j][0];
        conf = s_sorted[j][1];
        cx   = s_sorted[j][2];
        cy   = s_sorted[j][3];
        w    = s_sorted[j][4];
        h    = s_sorted[j][5];
    }
    int keep = (j < NCELL) && (conf > CONF_THR);

    float minx = cx - 0.5f * w, maxx = cx + 0.5f * w;
    float miny = cy - 0.5f * h, maxy = cy + 0.5f * h;
    float area = fabsf(w * h);

    for (int i = 0; i < NCELL; ++i) {
        int   keep_i = __shfl(keep, i);
        float icls   = __shfl(cls,  i);
        float iminx  = __shfl(minx, i);
        float imaxx  = __shfl(maxx, i);
        float iminy  = __shfl(miny, i);
        float imaxy  = __shfl(maxy, i);
        float iarea  = __shfl(area, i);

        if (j > i && keep && keep_i && cls == icls) {
            float ix0 = fmaxf(minx, iminx);
            float iy0 = fmaxf(miny, iminy);
            float ix1 = fminf(maxx, imaxx);
            float iy1 = fminf(maxy, imaxy);
            float iw = fmaxf(ix1 - ix0, 0.0f);
            float ih = fmaxf(iy1 - iy0, 0.0f);
            float inter = iw * ih;
            float iou = inter / (iarea + area - inter + EPS_IOU);
            if (iou >= IOU_THR) keep = 0;
        }
    }

    // ---- write: boxes (49*6, zeroed where suppressed) then keep (49) ----
    if (j < NCELL) {
        float kf = keep ? 1.0f : 0.0f;
        out[j * 6 + 0] = cls  * kf;
        out[j * 6 + 1] = conf * kf;
        out[j * 6 + 2] = cx   * kf;
        out[j * 6 + 3] = cy   * kf;
        out[j * 6 + 4] = w    * kf;
        out[j * 6 + 5] = h    * kf;
        out[NCELL * 6 + j] = kf;
    }
}

extern "C" void kernel_launch(void* const* d_in, const int* in_sizes, int n_in,
                              void* d_out, int out_size, void* d_ws, size_t ws_size,
                              hipStream_t stream) {
    const float* x = (const float*)d_in[0];
    float* out = (float*)d_out;
    yolo_decode_nms<<<1, 64, 0, stream>>>(x, out);
}